// Round 7
// baseline (269.817 us; speedup 1.0000x reference)
//
#include <hip/hip_runtime.h>

// ---------- types ----------
typedef __bf16 bf16x8 __attribute__((ext_vector_type(8)));
typedef float  f32x4  __attribute__((ext_vector_type(4)));
typedef unsigned short u16x8 __attribute__((ext_vector_type(8)));

#define IN_CH  256
#define OUT_CH 256
#define HIDDEN 2048
#define NB     8
#define NT     4000
#define NROW   32000   // NB*NT
#define F1LD   66      // f1t leading dim (odd word stride -> spread banks)

__device__ __forceinline__ unsigned short bfbits(float f) {
    __bf16 h = (__bf16)f;                       // native cvt (RTNE)
    return *reinterpret_cast<unsigned short*>(&h);
}
__device__ __forceinline__ float bf2f(unsigned short h) {
    return __uint_as_float(((unsigned)h) << 16);
}

#define GLOAD_LDS16(g, l) \
    __builtin_amdgcn_global_load_lds((const __attribute__((address_space(1))) void*)(g), \
                                     (__attribute__((address_space(3))) void*)(l), 16, 0, 0)

// ---------- 1. fp32 -> bf16 convert (weights) ----------
__global__ void cvt_kernel(const float* __restrict__ in,
                           unsigned short* __restrict__ out, int n4) {
    int i = blockIdx.x * blockDim.x + threadIdx.x;
    if (i >= n4) return;
    float4 v = reinterpret_cast<const float4*>(in)[i];
    ushort4 o;
    o.x = bfbits(v.x); o.y = bfbits(v.y); o.z = bfbits(v.z); o.w = bfbits(v.w);
    reinterpret_cast<ushort4*>(out)[i] = o;
}

// ---------- 2. partial mean/var reduction over T ----------
__global__ void reduce_kernel(const float* __restrict__ x,
                              float* __restrict__ psum, float* __restrict__ psq) {
    int c = threadIdx.x;
    int blk = blockIdx.x;
    int b = blk >> 5, tc = blk & 31;
    const float* base = x + ((size_t)b * NT + tc * 125) * IN_CH + c;
    float s = 0.f, q = 0.f;
    for (int t = 0; t < 125; ++t) {
        float v = base[(size_t)t * IN_CH];
        s += v; q += v * v;
    }
    psum[blk * IN_CH + c] = s;
    psq [blk * IN_CH + c] = q;
}

// ---------- 3. gate: mean/std -> logits -> probs -> losses ----------
__global__ __launch_bounds__(256) void gate_kernel(
    const float* __restrict__ psum, const float* __restrict__ psq,
    const float* __restrict__ gate_w, const float* __restrict__ gate_b,
    const float* __restrict__ tau, float* __restrict__ probs,
    float* __restrict__ losses) {
    __shared__ float gi[NB][2 * IN_CH];
    __shared__ float lgt[16];
    int tid = threadIdx.x;
    for (int b = 0; b < NB; ++b) {
        float s = 0.f, q = 0.f;
        for (int p = 0; p < 32; ++p) {
            s += psum[(b * 32 + p) * IN_CH + tid];
            q += psq [(b * 32 + p) * IN_CH + tid];
        }
        float mean = s * (1.f / 4000.f);
        float var  = (q - s * s * (1.f / 4000.f)) * (1.f / 3999.f);  // ddof=1
        gi[b][tid]          = mean;
        gi[b][IN_CH + tid]  = sqrtf(fmaxf(var, 0.f));
    }
    __syncthreads();
    if (tid < 16) {
        int b = tid >> 1, k = tid & 1;
        float d = 0.f;
        for (int i = 0; i < 2 * IN_CH; ++i) d += gi[b][i] * gate_w[k * 2 * IN_CH + i];
        lgt[tid] = tau[0] * (d + gate_b[k]);
    }
    __syncthreads();
    if (tid == 0) {
        float pr[16];
        float i0 = 0.f, i1 = 0.f, sp = 0.f;
        for (int b = 0; b < NB; ++b) {
            float a = lgt[b * 2], c2 = lgt[b * 2 + 1];
            float mx = fmaxf(a, c2);
            float e0 = expf(a - mx), e1 = expf(c2 - mx);
            float inv = 1.f / (e0 + e1);
            float q0 = e0 * inv, q1 = e1 * inv;
            pr[b * 2] = q0; pr[b * 2 + 1] = q1;
            i0 += q0; i1 += q1;
            float nrm = sqrtf(q0 * q0 + q1 * q1) + 1e-8f;
            sp += (q0 + q1) / nrm;
        }
        losses[0] = 0.1f * sp * (1.f / 8.f);
        i0 *= (1.f / 8.f); i1 *= (1.f / 8.f);
        float meanI = 0.5f * (i0 + i1);
        float stdI  = fabsf(i0 - i1) * 0.7071067811865476f;
        float cv = stdI / (meanI + 1e-8f);
        losses[1] = 0.01f * cv * cv;
        for (int t = 0; t < 16; ++t) probs[t] = pr[t];
    }
}

// ---------- 4. fused GEMM1(relu)+GEMM2, M=64, 4 waves, wave=64x64 ----------
// 500 blocks x 256 threads. Wave tile 64 rows x 64 oc (rt=4, ct=4).
// Register budget: xr 128 + acc2 64 + acc1 16 + temps ~40 = ~250 <= 256.
// (R6's 64x128 wave tile needed ~310 -> spilled ~50 regs -> WRITE_SIZE 84MB.)
// Per-chunk CU wall: 96 b128 LDS reads ~1150cyc vs 256 MFMA ~1240cyc (balanced).
__global__ __launch_bounds__(256, 1) void gemm_kernel(
    const float* __restrict__ x,
    const unsigned short* __restrict__ w1b,   // [2048][256] bf16
    const unsigned short* __restrict__ w2b,   // [256][2048] bf16
    const float* __restrict__ b1,
    unsigned short* __restrict__ msmall,      // [32000][256] bf16
    unsigned short* __restrict__ mfull) {
    __shared__ __align__(16) unsigned short w1c[2][64 * 256];   // 64 KB (dbuf)
    __shared__ __align__(16) unsigned short w2c[2][256 * 64];   // 64 KB (dbuf)
    __shared__ __align__(16) unsigned short f1t[64 * F1LD];     // 8.25 KB
    __shared__ float b1s[HIDDEN];                               // 8 KB

    const int tid   = threadIdx.x;
    const int lane  = tid & 63;
    const int wv    = tid >> 6;       // 0..3
    const int cq    = wv;             // column quarter (64 oc each)
    const int m0    = blockIdx.x * 64;
    const int l15   = lane & 15;
    const int lg    = lane >> 4;      // 0..3

    // ---- stage chunk 0 weights (buf 0): 32 segs each of w1c/w2c ----
#pragma unroll
    for (int i = 0; i < 8; ++i) {
        int seg = i * 4 + wv;                       // 0..31
        int r1 = seg * 2 + (lane >> 5);
        int c1 = ((lane & 31) * 8) ^ ((r1 & 7) << 3);
        GLOAD_LDS16(w1b + r1 * 256 + c1, &w1c[0][seg * 512]);
        int r2 = seg * 8 + (lane >> 3);
        int c2 = ((lane & 7) * 8) ^ ((r2 & 7) << 3);
        GLOAD_LDS16(w2b + (size_t)r2 * HIDDEN + c2, &w2c[0][seg * 512]);
    }
    // ---- bias to LDS ----
#pragma unroll
    for (int p = 0; p < 8; ++p) b1s[p * 256 + tid] = b1[p * 256 + tid];

    // ---- x fragments to registers: xr[rt][kk], rows m0 + rt*16 + l15 ----
    // (all 4 waves load the same 64-row tile; dup reads are L2-absorbed)
    bf16x8 xr[4][8];
#pragma unroll
    for (int rt = 0; rt < 4; ++rt) {
        const float* xrow = x + (size_t)(m0 + rt * 16 + l15) * IN_CH;
#pragma unroll
        for (int kk = 0; kk < 8; ++kk) {
            float4 v0 = *reinterpret_cast<const float4*>(xrow + kk * 32 + lg * 8);
            float4 v1 = *reinterpret_cast<const float4*>(xrow + kk * 32 + lg * 8 + 4);
            bf16x8 h;
            h[0] = (__bf16)v0.x; h[1] = (__bf16)v0.y; h[2] = (__bf16)v0.z; h[3] = (__bf16)v0.w;
            h[4] = (__bf16)v1.x; h[5] = (__bf16)v1.y; h[6] = (__bf16)v1.z; h[7] = (__bf16)v1.w;
            xr[rt][kk] = h;
        }
    }

    f32x4 acc2[4][4];
#pragma unroll
    for (int rt = 0; rt < 4; ++rt)
#pragma unroll
        for (int t = 0; t < 4; ++t) { acc2[rt][t][0]=0.f; acc2[rt][t][1]=0.f; acc2[rt][t][2]=0.f; acc2[rt][t][3]=0.f; }

    __syncthreads();   // chunk-0 staging drained + b1s ready

#pragma unroll 1
    for (int chunk = 0; chunk < 32; ++chunk) {
        const int buf = chunk & 1;
        // ---- issue next chunk's staging into buf^1 ----
        if (chunk < 31) {
            const int h0n = (chunk + 1) * 64;
            const unsigned short* w1s = w1b + (size_t)h0n * IN_CH;
            const unsigned short* w2s = w2b + h0n;
#pragma unroll
            for (int i = 0; i < 8; ++i) {
                int seg = i * 4 + wv;
                int r1 = seg * 2 + (lane >> 5);
                int c1 = ((lane & 31) * 8) ^ ((r1 & 7) << 3);
                GLOAD_LDS16(w1s + r1 * 256 + c1, &w1c[buf ^ 1][seg * 512]);
                int r2 = seg * 8 + (lane >> 3);
                int c2 = ((lane & 7) * 8) ^ ((r2 & 7) << 3);
                GLOAD_LDS16(w2s + (size_t)r2 * HIDDEN + c2, &w2c[buf ^ 1][seg * 512]);
            }
        }

        const unsigned short* W1 = w1c[buf];
        const unsigned short* W2 = w2c[buf];

        // ---- GEMM1: f1[64][64] = relu(x @ w1_chunk^T + b1); wave: 64r x 16h ----
        f32x4 acc1[4];
#pragma unroll
        for (int rt = 0; rt < 4; ++rt) { acc1[rt][0]=0.f; acc1[rt][1]=0.f; acc1[rt][2]=0.f; acc1[rt][3]=0.f; }
        {
            const int hl = cq * 16 + l15;
            const int hswz = (hl & 7) << 3;
#pragma unroll
            for (int kk = 0; kk < 8; ++kk) {
                const int kE = kk * 32 + lg * 8;
                bf16x8 bb = *reinterpret_cast<const bf16x8*>(&W1[hl * 256 + (kE ^ hswz)]);
#pragma unroll
                for (int rt = 0; rt < 4; ++rt)
                    acc1[rt] = __builtin_amdgcn_mfma_f32_16x16x32_bf16(
                        xr[rt][kk], bb, acc1[rt], 0, 0, 0);
            }
            // bias + relu -> f1t (col = hl fixed per lane)
            const float bias = b1s[chunk * 64 + hl];
#pragma unroll
            for (int rt = 0; rt < 4; ++rt)
#pragma unroll
                for (int r = 0; r < 4; ++r) {
                    float v = fmaxf(acc1[rt][r] + bias, 0.f);
                    int rr = rt * 16 + lg * 4 + r;
                    f1t[rr * F1LD + hl] = bfbits(v);
                }
        }
        __syncthreads();

        // ---- GEMM2: acc2 += f1 @ w2_chunk^T; wave: 64r x 64oc ----
#pragma unroll
        for (int kk = 0; kk < 2; ++kk) {
            const int kE = kk * 32 + lg * 8;
            bf16x8 a2[4];
#pragma unroll
            for (int rt = 0; rt < 4; ++rt)
                a2[rt] = *reinterpret_cast<const bf16x8*>(
                    &f1t[(rt * 16 + l15) * F1LD + kE]);
#pragma unroll
            for (int t = 0; t < 4; ++t) {
                int oc = cq * 64 + t * 16 + l15;
                bf16x8 b2 = *reinterpret_cast<const bf16x8*>(
                    &W2[oc * 64 + (kE ^ ((oc & 7) << 3))]);
#pragma unroll
                for (int rt = 0; rt < 4; ++rt)
                    acc2[rt][t] = __builtin_amdgcn_mfma_f32_16x16x32_bf16(
                        a2[rt], b2, acc2[rt][t], 0, 0, 0);
            }
        }

        if (chunk == 3) {   // hidden 0..255 done -> p1_small snapshot
#pragma unroll
            for (int t = 0; t < 4; ++t) {
                int oc = cq * 64 + t * 16 + l15;
#pragma unroll
                for (int rt = 0; rt < 4; ++rt)
#pragma unroll
                    for (int r = 0; r < 4; ++r) {
                        int rr = m0 + rt * 16 + lg * 4 + r;
                        msmall[(size_t)rr * OUT_CH + oc] = bfbits(acc2[rt][t][r]);
                    }
            }
        }
        __syncthreads();   // buf reads + f1t reads done; buf^1 staged
    }
    // final: p1_full
#pragma unroll
    for (int t = 0; t < 4; ++t) {
        int oc = cq * 64 + t * 16 + l15;
#pragma unroll
        for (int rt = 0; rt < 4; ++rt)
#pragma unroll
            for (int r = 0; r < 4; ++r) {
                int rr = m0 + rt * 16 + lg * 4 + r;
                mfull[(size_t)rr * OUT_CH + oc] = bfbits(acc2[rt][t][r]);
            }
    }
}

// ---------- 5. mix + depthwise conv (39 taps) + identity, LDS-staged ----------
#define CTT 128                 // t outputs per block
#define CROWS (CTT + 38)        // 166 staged rows
__global__ __launch_bounds__(512) void conv_kernel(
    const unsigned short* __restrict__ msmall,
    const unsigned short* __restrict__ mfull,
    const float* __restrict__ conv_w,   // [256][1][39]
    const float* __restrict__ probs,    // [8][2]
    float* __restrict__ out) {
    __shared__ __align__(16) unsigned short mix[CROWS * 256];

    const int tid = threadIdx.x;
    const int blk = blockIdx.x;
    const int b   = blk >> 5;
    const int t0  = (blk & 31) * CTT;
    const float p0 = probs[b * 2 + 0], p1 = probs[b * 2 + 1];

#pragma unroll
    for (int it = 0; it < 11; ++it) {
        int chunk = it * 512 + tid;
        if (it == 10 && tid >= 192) break;
        int e = chunk * 8;
        int s = e >> 8, c = e & 255;
        int t = t0 - 19 + s;
        u16x8 o;
        if (t >= 0 && t < NT) {
            size_t idx = ((size_t)b * NT + t) * OUT_CH + c;
            u16x8 vf = *reinterpret_cast<const u16x8*>(&mfull[idx]);
            u16x8 vs = *reinterpret_cast<const u16x8*>(&msmall[idx]);
#pragma unroll
            for (int k = 0; k < 8; ++k)
                o[k] = bfbits(p0 * bf2f(vf[k]) + p1 * bf2f(vs[k]));
        } else {
#pragma unroll
            for (int k = 0; k < 8; ++k) o[k] = 0;
        }
        *reinterpret_cast<u16x8*>(&mix[s * 256 + c]) = o;
    }
    __syncthreads();

    const int c  = tid & 255;
    const int th = tid >> 8;
    float cw[39];
#pragma unroll
    for (int j = 0; j < 39; ++j) cw[j] = conv_w[c * 39 + j];

#pragma unroll 1
    for (int g = 0; g < 8; ++g) {
        const int u0 = th * 64 + g * 8;
        float vwin[46];
#pragma unroll
        for (int i = 0; i < 46; ++i)
            vwin[i] = bf2f(mix[(u0 + i) * 256 + c]);
        float acc[8];
#pragma unroll
        for (int o = 0; o < 8; ++o) {
            float a = vwin[o + 19];
#pragma unroll
            for (int j = 0; j < 39; ++j)
                a += cw[j] * vwin[o + j];
            acc[o] = a;
        }
        const int tbase = t0 + u0;
#pragma unroll
        for (int o = 0; o < 8; ++o) {
            int t = tbase + o;
            if (t < NT)
                out[((size_t)b * NT + t) * OUT_CH + c] = acc[o];
        }
    }
}

// ---------- launch ----------
extern "C" void kernel_launch(void* const* d_in, const int* in_sizes, int n_in,
                              void* d_out, int out_size, void* d_ws, size_t ws_size,
                              hipStream_t stream) {
    const float* x      = (const float*)d_in[0];
    const float* w1     = (const float*)d_in[1];
    const float* b1     = (const float*)d_in[2];
    const float* w2     = (const float*)d_in[3];
    const float* conv_w = (const float*)d_in[4];
    const float* gate_w = (const float*)d_in[5];
    const float* gate_b = (const float*)d_in[6];
    const float* tau    = (const float*)d_in[7];
    float* out = (float*)d_out;

    char* ws = (char*)d_ws;
    unsigned short* w1b    = (unsigned short*)(ws);
    unsigned short* w2b    = (unsigned short*)(ws + 1048576);
    unsigned short* msmall = (unsigned short*)(ws + 2097152);
    unsigned short* mfull  = (unsigned short*)(ws + 2097152 + 16384000);
    float* psum  = (float*)(ws + 2097152 + 2 * 16384000);
    float* psq   = psum + 256 * 256;
    float* probs = psq + 256 * 256;

    cvt_kernel<<<dim3(512), dim3(256), 0, stream>>>(w1, w1b, 131072);
    cvt_kernel<<<dim3(512), dim3(256), 0, stream>>>(w2, w2b, 131072);
    reduce_kernel<<<dim3(256), dim3(256), 0, stream>>>(x, psum, psq);
    gate_kernel<<<dim3(1), dim3(256), 0, stream>>>(psum, psq, gate_w, gate_b, tau,
                                                   probs, out + 8192000);
    gemm_kernel<<<dim3(500), dim3(256), 0, stream>>>(x, w1b, w2b, b1, msmall, mfull);
    conv_kernel<<<dim3(256), dim3(512), 0, stream>>>(msmall, mfull, conv_w, probs, out);
}

// Round 8
// 251.059 us; speedup vs baseline: 1.0747x; 1.0747x over previous
//
#include <hip/hip_runtime.h>

// ---------- types ----------
typedef __bf16 bf16x8 __attribute__((ext_vector_type(8)));
typedef float  f32x4  __attribute__((ext_vector_type(4)));
typedef unsigned short u16x8 __attribute__((ext_vector_type(8)));

#define IN_CH  256
#define OUT_CH 256
#define HIDDEN 2048
#define NB     8
#define NT     4000
#define NROW   32000   // NB*NT
#define F1LD   66      // f1t leading dim (odd word stride -> spread banks)

__device__ __forceinline__ unsigned short bfbits(float f) {
    __bf16 h = (__bf16)f;                       // native cvt (RTNE)
    return *reinterpret_cast<unsigned short*>(&h);
}
__device__ __forceinline__ float bf2f(unsigned short h) {
    return __uint_as_float(((unsigned)h) << 16);
}

#define GLOAD_LDS16(g, l) \
    __builtin_amdgcn_global_load_lds((const __attribute__((address_space(1))) void*)(g), \
                                     (__attribute__((address_space(3))) void*)(l), 16, 0, 0)

// ---------- 1. fp32 -> bf16 convert (weights) ----------
__global__ void cvt_kernel(const float* __restrict__ in,
                           unsigned short* __restrict__ out, int n4) {
    int i = blockIdx.x * blockDim.x + threadIdx.x;
    if (i >= n4) return;
    float4 v = reinterpret_cast<const float4*>(in)[i];
    ushort4 o;
    o.x = bfbits(v.x); o.y = bfbits(v.y); o.z = bfbits(v.z); o.w = bfbits(v.w);
    reinterpret_cast<ushort4*>(out)[i] = o;
}

// ---------- 2. partial mean/var reduction over T ----------
__global__ void reduce_kernel(const float* __restrict__ x,
                              float* __restrict__ psum, float* __restrict__ psq) {
    int c = threadIdx.x;
    int blk = blockIdx.x;
    int b = blk >> 5, tc = blk & 31;
    const float* base = x + ((size_t)b * NT + tc * 125) * IN_CH + c;
    float s = 0.f, q = 0.f;
    for (int t = 0; t < 125; ++t) {
        float v = base[(size_t)t * IN_CH];
        s += v; q += v * v;
    }
    psum[blk * IN_CH + c] = s;
    psq [blk * IN_CH + c] = q;
}

// ---------- 3. gate: mean/std -> logits -> probs -> losses ----------
__global__ __launch_bounds__(256) void gate_kernel(
    const float* __restrict__ psum, const float* __restrict__ psq,
    const float* __restrict__ gate_w, const float* __restrict__ gate_b,
    const float* __restrict__ tau, float* __restrict__ probs,
    float* __restrict__ losses) {
    __shared__ float gi[NB][2 * IN_CH];
    __shared__ float lgt[16];
    int tid = threadIdx.x;
    for (int b = 0; b < NB; ++b) {
        float s = 0.f, q = 0.f;
        for (int p = 0; p < 32; ++p) {
            s += psum[(b * 32 + p) * IN_CH + tid];
            q += psq [(b * 32 + p) * IN_CH + tid];
        }
        float mean = s * (1.f / 4000.f);
        float var  = (q - s * s * (1.f / 4000.f)) * (1.f / 3999.f);  // ddof=1
        gi[b][tid]          = mean;
        gi[b][IN_CH + tid]  = sqrtf(fmaxf(var, 0.f));
    }
    __syncthreads();
    if (tid < 16) {
        int b = tid >> 1, k = tid & 1;
        float d = 0.f;
        for (int i = 0; i < 2 * IN_CH; ++i) d += gi[b][i] * gate_w[k * 2 * IN_CH + i];
        lgt[tid] = tau[0] * (d + gate_b[k]);
    }
    __syncthreads();
    if (tid == 0) {
        float pr[16];
        float i0 = 0.f, i1 = 0.f, sp = 0.f;
        for (int b = 0; b < NB; ++b) {
            float a = lgt[b * 2], c2 = lgt[b * 2 + 1];
            float mx = fmaxf(a, c2);
            float e0 = expf(a - mx), e1 = expf(c2 - mx);
            float inv = 1.f / (e0 + e1);
            float q0 = e0 * inv, q1 = e1 * inv;
            pr[b * 2] = q0; pr[b * 2 + 1] = q1;
            i0 += q0; i1 += q1;
            float nrm = sqrtf(q0 * q0 + q1 * q1) + 1e-8f;
            sp += (q0 + q1) / nrm;
        }
        losses[0] = 0.1f * sp * (1.f / 8.f);
        i0 *= (1.f / 8.f); i1 *= (1.f / 8.f);
        float meanI = 0.5f * (i0 + i1);
        float stdI  = fabsf(i0 - i1) * 0.7071067811865476f;
        float cv = stdI / (meanI + 1e-8f);
        losses[1] = 0.01f * cv * cv;
        for (int t = 0; t < 16; ++t) probs[t] = pr[t];
    }
}

// ---------- 4. fused GEMM1(relu)+GEMM2, M=64, 4 waves, 2 blocks/CU ----------
// 500 blocks x 256 threads. Wave tile 64 rows x 64 oc (rt=4, ct=4), VGPR ~224
// (R7: spill-free). LDS cut to 72.3 KB (single weight buffer, no b1s) so TWO
// blocks co-reside per CU -> 2 waves/SIMD. R7's wall was 1 wave/SIMD: zero
// latency hiding (Occupancy 11%, chunk wall ~7300cyc vs ~1150cyc of LDS work).
// The single-buffer stage->use gap is covered by the other block (m114).
__global__ __launch_bounds__(256, 1) void gemm_kernel(
    const float* __restrict__ x,
    const unsigned short* __restrict__ w1b,   // [2048][256] bf16
    const unsigned short* __restrict__ w2b,   // [256][2048] bf16
    const float* __restrict__ b1,
    unsigned short* __restrict__ msmall,      // [32000][256] bf16
    unsigned short* __restrict__ mfull) {
    __shared__ __align__(16) unsigned short w1c[64 * 256];   // 32 KB
    __shared__ __align__(16) unsigned short w2c[256 * 64];   // 32 KB
    __shared__ __align__(16) unsigned short f1t[64 * F1LD];  // 8.25 KB

    const int tid   = threadIdx.x;
    const int lane  = tid & 63;
    const int wv    = tid >> 6;       // 0..3
    const int cq    = wv;             // column quarter (64 oc each)
    const int m0    = blockIdx.x * 64;
    const int l15   = lane & 15;
    const int lg    = lane >> 4;      // 0..3
    const int hl    = cq * 16 + l15;  // GEMM1 hidden lane (fixed per thread)
    const int hswz  = (hl & 7) << 3;

    // ---- x fragments to registers: xr[rt][kk], rows m0 + rt*16 + l15 ----
    // (all 4 waves load the same 64-row tile; dup reads are L1/L2-absorbed)
    bf16x8 xr[4][8];
#pragma unroll
    for (int rt = 0; rt < 4; ++rt) {
        const float* xrow = x + (size_t)(m0 + rt * 16 + l15) * IN_CH;
#pragma unroll
        for (int kk = 0; kk < 8; ++kk) {
            float4 v0 = *reinterpret_cast<const float4*>(xrow + kk * 32 + lg * 8);
            float4 v1 = *reinterpret_cast<const float4*>(xrow + kk * 32 + lg * 8 + 4);
            bf16x8 h;
            h[0] = (__bf16)v0.x; h[1] = (__bf16)v0.y; h[2] = (__bf16)v0.z; h[3] = (__bf16)v0.w;
            h[4] = (__bf16)v1.x; h[5] = (__bf16)v1.y; h[6] = (__bf16)v1.z; h[7] = (__bf16)v1.w;
            xr[rt][kk] = h;
        }
    }

    f32x4 acc2[4][4];
#pragma unroll
    for (int rt = 0; rt < 4; ++rt)
#pragma unroll
        for (int t = 0; t < 4; ++t) { acc2[rt][t][0]=0.f; acc2[rt][t][1]=0.f; acc2[rt][t][2]=0.f; acc2[rt][t][3]=0.f; }

#pragma unroll 1
    for (int chunk = 0; chunk < 32; ++chunk) {
        // ---- stage THIS chunk's weights into the single buffer ----
        // (previous chunk's end barrier guarantees all reads completed)
        {
            const int h0 = chunk * 64;
            const unsigned short* w1s = w1b + (size_t)h0 * IN_CH;
            const unsigned short* w2s = w2b + h0;
#pragma unroll
            for (int i = 0; i < 8; ++i) {
                int seg = i * 4 + wv;                       // 0..31
                int r1 = seg * 2 + (lane >> 5);
                int c1 = ((lane & 31) * 8) ^ ((r1 & 7) << 3);
                GLOAD_LDS16(w1s + r1 * 256 + c1, &w1c[seg * 512]);
                int r2 = seg * 8 + (lane >> 3);
                int c2 = ((lane & 7) * 8) ^ ((r2 & 7) << 3);
                GLOAD_LDS16(w2s + (size_t)r2 * HIDDEN + c2, &w2c[seg * 512]);
            }
        }
        const float bias = b1[chunk * 64 + hl];   // per-lane scalar, L2-hit

        __syncthreads();   // [A] vmcnt drained -> weights ready

        // ---- GEMM1: f1[64][64] = relu(x @ w1_chunk^T + b1); wave: 64r x 16h ----
        f32x4 acc1[4];
#pragma unroll
        for (int rt = 0; rt < 4; ++rt) { acc1[rt][0]=0.f; acc1[rt][1]=0.f; acc1[rt][2]=0.f; acc1[rt][3]=0.f; }
#pragma unroll
        for (int kk = 0; kk < 8; ++kk) {
            const int kE = kk * 32 + lg * 8;
            bf16x8 bb = *reinterpret_cast<const bf16x8*>(&w1c[hl * 256 + (kE ^ hswz)]);
#pragma unroll
            for (int rt = 0; rt < 4; ++rt)
                acc1[rt] = __builtin_amdgcn_mfma_f32_16x16x32_bf16(
                    xr[rt][kk], bb, acc1[rt], 0, 0, 0);
        }
        // bias + relu -> f1t (col = hl fixed per lane)
#pragma unroll
        for (int rt = 0; rt < 4; ++rt)
#pragma unroll
            for (int r = 0; r < 4; ++r) {
                float v = fmaxf(acc1[rt][r] + bias, 0.f);
                int rr = rt * 16 + lg * 4 + r;
                f1t[rr * F1LD + hl] = bfbits(v);
            }

        __syncthreads();   // [B] f1t ready

        // ---- GEMM2: acc2 += f1 @ w2_chunk^T; wave: 64r x 64oc ----
#pragma unroll
        for (int kk = 0; kk < 2; ++kk) {
            const int kE = kk * 32 + lg * 8;
            bf16x8 a2[4];
#pragma unroll
            for (int rt = 0; rt < 4; ++rt)
                a2[rt] = *reinterpret_cast<const bf16x8*>(
                    &f1t[(rt * 16 + l15) * F1LD + kE]);
#pragma unroll
            for (int t = 0; t < 4; ++t) {
                int oc = cq * 64 + t * 16 + l15;
                bf16x8 b2 = *reinterpret_cast<const bf16x8*>(
                    &w2c[oc * 64 + (kE ^ ((oc & 7) << 3))]);
#pragma unroll
                for (int rt = 0; rt < 4; ++rt)
                    acc2[rt][t] = __builtin_amdgcn_mfma_f32_16x16x32_bf16(
                        a2[rt], b2, acc2[rt][t], 0, 0, 0);
            }
        }

        if (chunk == 3) {   // hidden 0..255 done -> p1_small snapshot
#pragma unroll
            for (int t = 0; t < 4; ++t) {
                int oc = cq * 64 + t * 16 + l15;
#pragma unroll
                for (int rt = 0; rt < 4; ++rt)
#pragma unroll
                    for (int r = 0; r < 4; ++r) {
                        int rr = m0 + rt * 16 + lg * 4 + r;
                        msmall[(size_t)rr * OUT_CH + oc] = bfbits(acc2[rt][t][r]);
                    }
            }
        }

        __syncthreads();   // [C] w1c/w2c/f1t reads done -> next stage may overwrite
    }
    // final: p1_full
#pragma unroll
    for (int t = 0; t < 4; ++t) {
        int oc = cq * 64 + t * 16 + l15;
#pragma unroll
        for (int rt = 0; rt < 4; ++rt)
#pragma unroll
            for (int r = 0; r < 4; ++r) {
                int rr = m0 + rt * 16 + lg * 4 + r;
                mfull[(size_t)rr * OUT_CH + oc] = bfbits(acc2[rt][t][r]);
            }
    }
}

// ---------- 5. mix + depthwise conv (39 taps) + identity, LDS-staged ----------
#define CTT 128                 // t outputs per block
#define CROWS (CTT + 38)        // 166 staged rows
__global__ __launch_bounds__(512) void conv_kernel(
    const unsigned short* __restrict__ msmall,
    const unsigned short* __restrict__ mfull,
    const float* __restrict__ conv_w,   // [256][1][39]
    const float* __restrict__ probs,    // [8][2]
    float* __restrict__ out) {
    __shared__ __align__(16) unsigned short mix[CROWS * 256];

    const int tid = threadIdx.x;
    const int blk = blockIdx.x;
    const int b   = blk >> 5;
    const int t0  = (blk & 31) * CTT;
    const float p0 = probs[b * 2 + 0], p1 = probs[b * 2 + 1];

#pragma unroll
    for (int it = 0; it < 11; ++it) {
        int chunk = it * 512 + tid;
        if (it == 10 && tid >= 192) break;
        int e = chunk * 8;
        int s = e >> 8, c = e & 255;
        int t = t0 - 19 + s;
        u16x8 o;
        if (t >= 0 && t < NT) {
            size_t idx = ((size_t)b * NT + t) * OUT_CH + c;
            u16x8 vf = *reinterpret_cast<const u16x8*>(&mfull[idx]);
            u16x8 vs = *reinterpret_cast<const u16x8*>(&msmall[idx]);
#pragma unroll
            for (int k = 0; k < 8; ++k)
                o[k] = bfbits(p0 * bf2f(vf[k]) + p1 * bf2f(vs[k]));
        } else {
#pragma unroll
            for (int k = 0; k < 8; ++k) o[k] = 0;
        }
        *reinterpret_cast<u16x8*>(&mix[s * 256 + c]) = o;
    }
    __syncthreads();

    const int c  = tid & 255;
    const int th = tid >> 8;
    float cw[39];
#pragma unroll
    for (int j = 0; j < 39; ++j) cw[j] = conv_w[c * 39 + j];

#pragma unroll 1
    for (int g = 0; g < 8; ++g) {
        const int u0 = th * 64 + g * 8;
        float vwin[46];
#pragma unroll
        for (int i = 0; i < 46; ++i)
            vwin[i] = bf2f(mix[(u0 + i) * 256 + c]);
        float acc[8];
#pragma unroll
        for (int o = 0; o < 8; ++o) {
            float a = vwin[o + 19];
#pragma unroll
            for (int j = 0; j < 39; ++j)
                a += cw[j] * vwin[o + j];
            acc[o] = a;
        }
        const int tbase = t0 + u0;
#pragma unroll
        for (int o = 0; o < 8; ++o) {
            int t = tbase + o;
            if (t < NT)
                out[((size_t)b * NT + t) * OUT_CH + c] = acc[o];
        }
    }
}

// ---------- launch ----------
extern "C" void kernel_launch(void* const* d_in, const int* in_sizes, int n_in,
                              void* d_out, int out_size, void* d_ws, size_t ws_size,
                              hipStream_t stream) {
    const float* x      = (const float*)d_in[0];
    const float* w1     = (const float*)d_in[1];
    const float* b1     = (const float*)d_in[2];
    const float* w2     = (const float*)d_in[3];
    const float* conv_w = (const float*)d_in[4];
    const float* gate_w = (const float*)d_in[5];
    const float* gate_b = (const float*)d_in[6];
    const float* tau    = (const float*)d_in[7];
    float* out = (float*)d_out;

    char* ws = (char*)d_ws;
    unsigned short* w1b    = (unsigned short*)(ws);
    unsigned short* w2b    = (unsigned short*)(ws + 1048576);
    unsigned short* msmall = (unsigned short*)(ws + 2097152);
    unsigned short* mfull  = (unsigned short*)(ws + 2097152 + 16384000);
    float* psum  = (float*)(ws + 2097152 + 2 * 16384000);
    float* psq   = psum + 256 * 256;
    float* probs = psq + 256 * 256;

    cvt_kernel<<<dim3(512), dim3(256), 0, stream>>>(w1, w1b, 131072);
    cvt_kernel<<<dim3(512), dim3(256), 0, stream>>>(w2, w2b, 131072);
    reduce_kernel<<<dim3(256), dim3(256), 0, stream>>>(x, psum, psq);
    gate_kernel<<<dim3(1), dim3(256), 0, stream>>>(psum, psq, gate_w, gate_b, tau,
                                                   probs, out + 8192000);
    gemm_kernel<<<dim3(500), dim3(256), 0, stream>>>(x, w1b, w2b, b1, msmall, mfull);
    conv_kernel<<<dim3(256), dim3(512), 0, stream>>>(msmall, mfull, conv_w, probs, out);
}

// Round 9
// 181.968 us; speedup vs baseline: 1.4828x; 1.3797x over previous
//
#include <hip/hip_runtime.h>

// ---------- types ----------
typedef __bf16 bf16x8 __attribute__((ext_vector_type(8)));
typedef float  f32x4  __attribute__((ext_vector_type(4)));
typedef unsigned short u16x8 __attribute__((ext_vector_type(8)));

#define IN_CH  256
#define OUT_CH 256
#define HIDDEN 2048
#define NB     8
#define NT     4000
#define NROW   32000   // NB*NT
#define F1LD   66      // f1t leading dim (odd word stride -> spread banks)

__device__ __forceinline__ unsigned short bfbits(float f) {
    __bf16 h = (__bf16)f;                       // native cvt (RTNE)
    return *reinterpret_cast<unsigned short*>(&h);
}
__device__ __forceinline__ float bf2f(unsigned short h) {
    return __uint_as_float(((unsigned)h) << 16);
}

#define GLOAD_LDS16(g, l) \
    __builtin_amdgcn_global_load_lds((const __attribute__((address_space(1))) void*)(g), \
                                     (__attribute__((address_space(3))) void*)(l), 16, 0, 0)

// ---------- 1. fp32 -> bf16 convert (weights) ----------
__global__ void cvt_kernel(const float* __restrict__ in,
                           unsigned short* __restrict__ out, int n4) {
    int i = blockIdx.x * blockDim.x + threadIdx.x;
    if (i >= n4) return;
    float4 v = reinterpret_cast<const float4*>(in)[i];
    ushort4 o;
    o.x = bfbits(v.x); o.y = bfbits(v.y); o.z = bfbits(v.z); o.w = bfbits(v.w);
    reinterpret_cast<ushort4*>(out)[i] = o;
}

// ---------- 2. partial mean/var reduction over T ----------
__global__ void reduce_kernel(const float* __restrict__ x,
                              float* __restrict__ psum, float* __restrict__ psq) {
    int c = threadIdx.x;
    int blk = blockIdx.x;
    int b = blk >> 5, tc = blk & 31;
    const float* base = x + ((size_t)b * NT + tc * 125) * IN_CH + c;
    float s = 0.f, q = 0.f;
    for (int t = 0; t < 125; ++t) {
        float v = base[(size_t)t * IN_CH];
        s += v; q += v * v;
    }
    psum[blk * IN_CH + c] = s;
    psq [blk * IN_CH + c] = q;
}

// ---------- 3. gate: mean/std -> logits -> probs -> losses ----------
__global__ __launch_bounds__(256) void gate_kernel(
    const float* __restrict__ psum, const float* __restrict__ psq,
    const float* __restrict__ gate_w, const float* __restrict__ gate_b,
    const float* __restrict__ tau, float* __restrict__ probs,
    float* __restrict__ losses) {
    __shared__ float gi[NB][2 * IN_CH];
    __shared__ float lgt[16];
    int tid = threadIdx.x;
    for (int b = 0; b < NB; ++b) {
        float s = 0.f, q = 0.f;
        for (int p = 0; p < 32; ++p) {
            s += psum[(b * 32 + p) * IN_CH + tid];
            q += psq [(b * 32 + p) * IN_CH + tid];
        }
        float mean = s * (1.f / 4000.f);
        float var  = (q - s * s * (1.f / 4000.f)) * (1.f / 3999.f);  // ddof=1
        gi[b][tid]          = mean;
        gi[b][IN_CH + tid]  = sqrtf(fmaxf(var, 0.f));
    }
    __syncthreads();
    if (tid < 16) {
        int b = tid >> 1, k = tid & 1;
        float d = 0.f;
        for (int i = 0; i < 2 * IN_CH; ++i) d += gi[b][i] * gate_w[k * 2 * IN_CH + i];
        lgt[tid] = tau[0] * (d + gate_b[k]);
    }
    __syncthreads();
    if (tid == 0) {
        float pr[16];
        float i0 = 0.f, i1 = 0.f, sp = 0.f;
        for (int b = 0; b < NB; ++b) {
            float a = lgt[b * 2], c2 = lgt[b * 2 + 1];
            float mx = fmaxf(a, c2);
            float e0 = expf(a - mx), e1 = expf(c2 - mx);
            float inv = 1.f / (e0 + e1);
            float q0 = e0 * inv, q1 = e1 * inv;
            pr[b * 2] = q0; pr[b * 2 + 1] = q1;
            i0 += q0; i1 += q1;
            float nrm = sqrtf(q0 * q0 + q1 * q1) + 1e-8f;
            sp += (q0 + q1) / nrm;
        }
        losses[0] = 0.1f * sp * (1.f / 8.f);
        i0 *= (1.f / 8.f); i1 *= (1.f / 8.f);
        float meanI = 0.5f * (i0 + i1);
        float stdI  = fabsf(i0 - i1) * 0.7071067811865476f;
        float cv = stdI / (meanI + 1e-8f);
        losses[1] = 0.01f * cv * cv;
        for (int t = 0; t < 16; ++t) probs[t] = pr[t];
    }
}

// ---------- 4. fused GEMM1(relu)+GEMM2, M=64, wave=32r x 128oc ----------
// 500 blocks x 256 threads (4 waves = 2 rb x 2 ch). Register budget per wave:
// xr 64 + acc2 64 + acc1 16 + temps ~60 = ~205 <= 256 -> 2 waves/SIMD.
// (Occupancy model from R2/R3/R7/R8: waves/SIMD = 512 / (archVGPR + AGPR);
//  R8 was 220+80=300 -> 1 wave/SIMD -> no latency hiding, 175us.)
// LDS 72.25 KB -> 2 blocks/CU; all 500 blocks co-resident, anti-phased.
__global__ __launch_bounds__(256, 2) void gemm_kernel(
    const float* __restrict__ x,
    const unsigned short* __restrict__ w1b,   // [2048][256] bf16
    const unsigned short* __restrict__ w2b,   // [256][2048] bf16
    const float* __restrict__ b1,
    unsigned short* __restrict__ msmall,      // [32000][256] bf16
    unsigned short* __restrict__ mfull) {
    __shared__ __align__(16) unsigned short w1c[64 * 256];   // 32 KB
    __shared__ __align__(16) unsigned short w2c[256 * 64];   // 32 KB
    __shared__ __align__(16) unsigned short f1t[64 * F1LD];  // 8.25 KB

    const int tid   = threadIdx.x;
    const int lane  = tid & 63;
    const int wv    = tid >> 6;       // 0..3
    const int rb    = wv & 1;         // 32-row band
    const int ch    = wv >> 1;        // 0..1 oc half (128 each)
    const int m0    = blockIdx.x * 64;
    const int l15   = lane & 15;
    const int lg    = lane >> 4;      // 0..3

    // ---- x fragments to registers: xr[rt][kk], rows m0 + rb*32 + rt*16 + l15 ----
    bf16x8 xr[2][8];
#pragma unroll
    for (int rt = 0; rt < 2; ++rt) {
        const float* xrow = x + (size_t)(m0 + rb * 32 + rt * 16 + l15) * IN_CH;
#pragma unroll
        for (int kk = 0; kk < 8; ++kk) {
            float4 v0 = *reinterpret_cast<const float4*>(xrow + kk * 32 + lg * 8);
            float4 v1 = *reinterpret_cast<const float4*>(xrow + kk * 32 + lg * 8 + 4);
            bf16x8 h;
            h[0] = (__bf16)v0.x; h[1] = (__bf16)v0.y; h[2] = (__bf16)v0.z; h[3] = (__bf16)v0.w;
            h[4] = (__bf16)v1.x; h[5] = (__bf16)v1.y; h[6] = (__bf16)v1.z; h[7] = (__bf16)v1.w;
            xr[rt][kk] = h;
        }
    }

    f32x4 acc2[2][8];
#pragma unroll
    for (int rt = 0; rt < 2; ++rt)
#pragma unroll
        for (int t = 0; t < 8; ++t) { acc2[rt][t][0]=0.f; acc2[rt][t][1]=0.f; acc2[rt][t][2]=0.f; acc2[rt][t][3]=0.f; }

#pragma unroll 1
    for (int chunk = 0; chunk < 32; ++chunk) {
        // ---- stage THIS chunk's weights into the single buffer ----
        {
            const int h0 = chunk * 64;
            const unsigned short* w1s = w1b + (size_t)h0 * IN_CH;
            const unsigned short* w2s = w2b + h0;
#pragma unroll
            for (int i = 0; i < 8; ++i) {
                int seg = i * 4 + wv;                       // 0..31
                int r1 = seg * 2 + (lane >> 5);
                int c1 = ((lane & 31) * 8) ^ ((r1 & 7) << 3);
                GLOAD_LDS16(w1s + r1 * 256 + c1, &w1c[seg * 512]);
                int r2 = seg * 8 + (lane >> 3);
                int c2 = ((lane & 7) * 8) ^ ((r2 & 7) << 3);
                GLOAD_LDS16(w2s + (size_t)r2 * HIDDEN + c2, &w2c[seg * 512]);
            }
        }

        __syncthreads();   // [A] vmcnt drained -> weights ready

        // ---- GEMM1: f1[64][64]; wave (rb,ch): rows rb*32+.., h ch*32+ht*16+l15 ----
        f32x4 acc1[2][2];
#pragma unroll
        for (int rt = 0; rt < 2; ++rt)
#pragma unroll
            for (int ht = 0; ht < 2; ++ht) { acc1[rt][ht][0]=0.f; acc1[rt][ht][1]=0.f; acc1[rt][ht][2]=0.f; acc1[rt][ht][3]=0.f; }
#pragma unroll
        for (int kk = 0; kk < 8; ++kk) {
            const int kE = kk * 32 + lg * 8;
            bf16x8 bb[2];
#pragma unroll
            for (int ht = 0; ht < 2; ++ht) {
                const int hl = ch * 32 + ht * 16 + l15;
                bb[ht] = *reinterpret_cast<const bf16x8*>(
                    &w1c[hl * 256 + (kE ^ ((hl & 7) << 3))]);
            }
#pragma unroll
            for (int rt = 0; rt < 2; ++rt)
#pragma unroll
                for (int ht = 0; ht < 2; ++ht)
                    acc1[rt][ht] = __builtin_amdgcn_mfma_f32_16x16x32_bf16(
                        xr[rt][kk], bb[ht], acc1[rt][ht], 0, 0, 0);
        }
        // bias + relu -> f1t
#pragma unroll
        for (int ht = 0; ht < 2; ++ht) {
            const int hl = ch * 32 + ht * 16 + l15;
            const float bias = b1[chunk * 64 + hl];   // L2-hit scalar
#pragma unroll
            for (int rt = 0; rt < 2; ++rt)
#pragma unroll
                for (int r = 0; r < 4; ++r) {
                    float v = fmaxf(acc1[rt][ht][r] + bias, 0.f);
                    int rr = rb * 32 + rt * 16 + lg * 4 + r;
                    f1t[rr * F1LD + hl] = bfbits(v);
                }
        }

        __syncthreads();   // [B] f1t ready

        // ---- GEMM2: acc2 += f1 @ w2_chunk^T; wave: 32r x 128oc ----
#pragma unroll
        for (int kk = 0; kk < 2; ++kk) {
            const int kE = kk * 32 + lg * 8;
            bf16x8 a2[2];
#pragma unroll
            for (int rt = 0; rt < 2; ++rt)
                a2[rt] = *reinterpret_cast<const bf16x8*>(
                    &f1t[(rb * 32 + rt * 16 + l15) * F1LD + kE]);
#pragma unroll
            for (int t = 0; t < 8; ++t) {
                int oc = ch * 128 + t * 16 + l15;
                bf16x8 b2 = *reinterpret_cast<const bf16x8*>(
                    &w2c[oc * 64 + (kE ^ ((oc & 7) << 3))]);
#pragma unroll
                for (int rt = 0; rt < 2; ++rt)
                    acc2[rt][t] = __builtin_amdgcn_mfma_f32_16x16x32_bf16(
                        a2[rt], b2, acc2[rt][t], 0, 0, 0);
            }
        }

        if (chunk == 3) {   // hidden 0..255 done -> p1_small snapshot
#pragma unroll
            for (int t = 0; t < 8; ++t) {
                int oc = ch * 128 + t * 16 + l15;
#pragma unroll
                for (int rt = 0; rt < 2; ++rt)
#pragma unroll
                    for (int r = 0; r < 4; ++r) {
                        int rr = m0 + rb * 32 + rt * 16 + lg * 4 + r;
                        msmall[(size_t)rr * OUT_CH + oc] = bfbits(acc2[rt][t][r]);
                    }
            }
        }

        __syncthreads();   // [C] w1c/w2c/f1t reads done -> next stage may overwrite
    }
    // final: p1_full
#pragma unroll
    for (int t = 0; t < 8; ++t) {
        int oc = ch * 128 + t * 16 + l15;
#pragma unroll
        for (int rt = 0; rt < 2; ++rt)
#pragma unroll
            for (int r = 0; r < 4; ++r) {
                int rr = m0 + rb * 32 + rt * 16 + lg * 4 + r;
                mfull[(size_t)rr * OUT_CH + oc] = bfbits(acc2[rt][t][r]);
            }
    }
}

// ---------- 5. mix + depthwise conv (39 taps) + identity, LDS-staged ----------
#define CTT 128                 // t outputs per block
#define CROWS (CTT + 38)        // 166 staged rows
__global__ __launch_bounds__(512) void conv_kernel(
    const unsigned short* __restrict__ msmall,
    const unsigned short* __restrict__ mfull,
    const float* __restrict__ conv_w,   // [256][1][39]
    const float* __restrict__ probs,    // [8][2]
    float* __restrict__ out) {
    __shared__ __align__(16) unsigned short mix[CROWS * 256];

    const int tid = threadIdx.x;
    const int blk = blockIdx.x;
    const int b   = blk >> 5;
    const int t0  = (blk & 31) * CTT;
    const float p0 = probs[b * 2 + 0], p1 = probs[b * 2 + 1];

#pragma unroll
    for (int it = 0; it < 11; ++it) {
        int chunk = it * 512 + tid;
        if (it == 10 && tid >= 192) break;
        int e = chunk * 8;
        int s = e >> 8, c = e & 255;
        int t = t0 - 19 + s;
        u16x8 o;
        if (t >= 0 && t < NT) {
            size_t idx = ((size_t)b * NT + t) * OUT_CH + c;
            u16x8 vf = *reinterpret_cast<const u16x8*>(&mfull[idx]);
            u16x8 vs = *reinterpret_cast<const u16x8*>(&msmall[idx]);
#pragma unroll
            for (int k = 0; k < 8; ++k)
                o[k] = bfbits(p0 * bf2f(vf[k]) + p1 * bf2f(vs[k]));
        } else {
#pragma unroll
            for (int k = 0; k < 8; ++k) o[k] = 0;
        }
        *reinterpret_cast<u16x8*>(&mix[s * 256 + c]) = o;
    }
    __syncthreads();

    const int c  = tid & 255;
    const int th = tid >> 8;
    float cw[39];
#pragma unroll
    for (int j = 0; j < 39; ++j) cw[j] = conv_w[c * 39 + j];

#pragma unroll 1
    for (int g = 0; g < 8; ++g) {
        const int u0 = th * 64 + g * 8;
        float vwin[46];
#pragma unroll
        for (int i = 0; i < 46; ++i)
            vwin[i] = bf2f(mix[(u0 + i) * 256 + c]);
        float acc[8];
#pragma unroll
        for (int o = 0; o < 8; ++o) {
            float a = vwin[o + 19];
#pragma unroll
            for (int j = 0; j < 39; ++j)
                a += cw[j] * vwin[o + j];
            acc[o] = a;
        }
        const int tbase = t0 + u0;
#pragma unroll
        for (int o = 0; o < 8; ++o) {
            int t = tbase + o;
            if (t < NT)
                out[((size_t)b * NT + t) * OUT_CH + c] = acc[o];
        }
    }
}

// ---------- launch ----------
extern "C" void kernel_launch(void* const* d_in, const int* in_sizes, int n_in,
                              void* d_out, int out_size, void* d_ws, size_t ws_size,
                              hipStream_t stream) {
    const float* x      = (const float*)d_in[0];
    const float* w1     = (const float*)d_in[1];
    const float* b1     = (const float*)d_in[2];
    const float* w2     = (const float*)d_in[3];
    const float* conv_w = (const float*)d_in[4];
    const float* gate_w = (const float*)d_in[5];
    const float* gate_b = (const float*)d_in[6];
    const float* tau    = (const float*)d_in[7];
    float* out = (float*)d_out;

    char* ws = (char*)d_ws;
    unsigned short* w1b    = (unsigned short*)(ws);
    unsigned short* w2b    = (unsigned short*)(ws + 1048576);
    unsigned short* msmall = (unsigned short*)(ws + 2097152);
    unsigned short* mfull  = (unsigned short*)(ws + 2097152 + 16384000);
    float* psum  = (float*)(ws + 2097152 + 2 * 16384000);
    float* psq   = psum + 256 * 256;
    float* probs = psq + 256 * 256;

    cvt_kernel<<<dim3(512), dim3(256), 0, stream>>>(w1, w1b, 131072);
    cvt_kernel<<<dim3(512), dim3(256), 0, stream>>>(w2, w2b, 131072);
    reduce_kernel<<<dim3(256), dim3(256), 0, stream>>>(x, psum, psq);
    gate_kernel<<<dim3(1), dim3(256), 0, stream>>>(psum, psq, gate_w, gate_b, tau,
                                                   probs, out + 8192000);
    gemm_kernel<<<dim3(500), dim3(256), 0, stream>>>(x, w1b, w2b, b1, msmall, mfull);
    conv_kernel<<<dim3(256), dim3(512), 0, stream>>>(msmall, mfull, conv_w, probs, out);
}